// Round 1
// baseline (62.038 us; speedup 1.0000x reference)
//
#include <hip/hip_runtime.h>

// det of row-major 3x3 matrices: in [N,9] f32 -> out [N,1] f32.
// Memory-bound: 302 MB read + 33.5 MB write. Strategy: LDS-stage each
// block's 256 rows (2304 floats = 576 float4) with coalesced float4 loads,
// then stride-9 LDS reads (odd stride -> conflict-free) + cofactor det.

#define TPB 256
#define ROWS_PER_BLOCK 256
#define FLOATS_PER_TILE (ROWS_PER_BLOCK * 9)   // 2304
#define VEC4_PER_TILE (FLOATS_PER_TILE / 4)    // 576

__global__ __launch_bounds__(TPB) void det3_kernel(const float* __restrict__ x,
                                                   float* __restrict__ out,
                                                   long long n) {
    __shared__ float s[FLOATS_PER_TILE];
    const int tid = threadIdx.x;
    const long long row0 = (long long)blockIdx.x * ROWS_PER_BLOCK;

    if (row0 + ROWS_PER_BLOCK <= n) {
        // Full tile: vectorized cooperative load. Tile base byte offset is
        // blockIdx * 9216, which is 16B-aligned.
        const float4* g4 = reinterpret_cast<const float4*>(x + row0 * 9);
        float4* s4 = reinterpret_cast<float4*>(s);
        // 576 = 2*256 + 64
        s4[tid] = g4[tid];
        s4[tid + 256] = g4[tid + 256];
        if (tid < VEC4_PER_TILE - 512) s4[tid + 512] = g4[tid + 512];
    } else {
        // Tail tile (not hit for N = 2^23, kept for generality): scalar loads.
        const long long base = row0 * 9;
        const long long limit = n * 9;
        for (int j = tid; j < FLOATS_PER_TILE; j += TPB) {
            const long long gi = base + j;
            s[j] = (gi < limit) ? x[gi] : 0.0f;
        }
    }
    __syncthreads();

    const long long row = row0 + tid;
    if (row < n) {
        const float* m = &s[tid * 9];
        const float a = m[0], b = m[1], c = m[2];
        const float d = m[3], e = m[4], f = m[5];
        const float g = m[6], h = m[7], i = m[8];
        const float det = a * (e * i - f * h)
                        - b * (d * i - f * g)
                        + c * (d * h - e * g);
        out[row] = det;
    }
}

extern "C" void kernel_launch(void* const* d_in, const int* in_sizes, int n_in,
                              void* d_out, int out_size, void* d_ws, size_t ws_size,
                              hipStream_t stream) {
    const float* x = (const float*)d_in[0];
    float* out = (float*)d_out;
    const long long n = (long long)in_sizes[0] / 9;
    const int blocks = (int)((n + ROWS_PER_BLOCK - 1) / ROWS_PER_BLOCK);
    det3_kernel<<<blocks, TPB, 0, stream>>>(x, out, n);
}

// Round 3
// 55.777 us; speedup vs baseline: 1.1123x; 1.1123x over previous
//
#include <hip/hip_runtime.h>

// det of row-major 3x3 matrices: in [N,9] f32 -> out [N,1] f32.
// Memory-bound streaming: 302 MB read + 33.5 MB write, ~15 FLOP/row.
// R3: 4 rows/thread, 1024-row tiles. Staging = 9x fully-coalesced float4
// cooperative loads into LDS; per-thread reads = 9x ds_read_b128 (144B
// stride); stores = 1x dwordx4 nontemporal per thread. Uses clang
// ext_vector_type (HIP float4 is a class -> rejected by the builtin).

typedef float fx4 __attribute__((ext_vector_type(4)));

#define TPB 256
#define ROWS_PER_THREAD 4
#define ROWS_PER_BLOCK (TPB * ROWS_PER_THREAD)       // 1024
#define FLOATS_PER_TILE (ROWS_PER_BLOCK * 9)         // 9216

__global__ __launch_bounds__(TPB) void det3_kernel(const float* __restrict__ x,
                                                   float* __restrict__ out,
                                                   long long n) {
    __shared__ float s[FLOATS_PER_TILE];
    const int tid = threadIdx.x;
    const long long row0 = (long long)blockIdx.x * ROWS_PER_BLOCK;

    if (row0 + ROWS_PER_BLOCK <= n) {
        // Full tile: 9 fully-coalesced 16B loads per thread.
        // Tile base byte offset = blockIdx * 36864 -> 16B-aligned.
        const fx4* __restrict__ g4 = reinterpret_cast<const fx4*>(x + row0 * 9);
        fx4* s4 = reinterpret_cast<fx4*>(s);
#pragma unroll
        for (int k = 0; k < 9; ++k) {
            s4[tid + k * TPB] = g4[tid + k * TPB];
        }
        __syncthreads();

        // Each thread: rows 4*tid .. 4*tid+3 = 36 floats = 9 ds_read_b128.
        fx4 q[9];
        const fx4* sv = reinterpret_cast<const fx4*>(&s[tid * 36]);
#pragma unroll
        for (int k = 0; k < 9; ++k) q[k] = sv[k];
        const float* m = reinterpret_cast<const float*>(q);

        fx4 r;
#pragma unroll
        for (int rrow = 0; rrow < ROWS_PER_THREAD; ++rrow) {
            const float* mm = m + rrow * 9;
            const float a = mm[0], b = mm[1], c = mm[2];
            const float d = mm[3], e = mm[4], f = mm[5];
            const float g = mm[6], h = mm[7], i = mm[8];
            r[rrow] = a * (e * i - f * h)
                    - b * (d * i - f * g)
                    + c * (d * h - e * g);
        }
        fx4* out4 = reinterpret_cast<fx4*>(out + row0);
        __builtin_nontemporal_store(r, &out4[tid]);
    } else {
        // Tail tile (not hit for N = 2^23): scalar path.
        const long long limit = n * 9;
        for (int j = tid; j < FLOATS_PER_TILE; j += TPB) {
            const long long gi = row0 * 9 + j;
            s[j] = (gi < limit) ? x[gi] : 0.0f;
        }
        __syncthreads();
#pragma unroll
        for (int rrow = 0; rrow < ROWS_PER_THREAD; ++rrow) {
            const long long row = row0 + (long long)tid * ROWS_PER_THREAD + rrow;
            if (row < n) {
                const float* mm = &s[(tid * ROWS_PER_THREAD + rrow) * 9];
                const float a = mm[0], b = mm[1], c = mm[2];
                const float d = mm[3], e = mm[4], f = mm[5];
                const float g = mm[6], h = mm[7], i = mm[8];
                out[row] = a * (e * i - f * h)
                         - b * (d * i - f * g)
                         + c * (d * h - e * g);
            }
        }
    }
}

extern "C" void kernel_launch(void* const* d_in, const int* in_sizes, int n_in,
                              void* d_out, int out_size, void* d_ws, size_t ws_size,
                              hipStream_t stream) {
    const float* x = (const float*)d_in[0];
    float* out = (float*)d_out;
    const long long n = (long long)in_sizes[0] / 9;
    const int blocks = (int)((n + ROWS_PER_BLOCK - 1) / ROWS_PER_BLOCK);
    det3_kernel<<<blocks, TPB, 0, stream>>>(x, out, n);
}